// Round 1
// 741.496 us; speedup vs baseline: 1.2756x; 1.2756x over previous
//
#include <hip/hip_runtime.h>
#include <stdint.h>

#define NS_TOK 16384
#define DIM 2048
#define OUTD 2048
#define NEXP 8
#define NPAIR 28

typedef __attribute__((ext_vector_type(8))) short short8;
typedef __attribute__((ext_vector_type(4))) float f32x4;
typedef __attribute__((address_space(3))) uint32_t lds_u32;
typedef __attribute__((address_space(1))) const uint32_t gbl_u32;

__device__ __forceinline__ unsigned short f2bf(float f) {
  union { float f; uint32_t u; } v; v.f = f;
  uint32_t r = v.u + 0x7fffu + ((v.u >> 16) & 1u);   // RNE
  return (unsigned short)(r >> 16);
}

__device__ __forceinline__ void gld_lds16(const void* g, void* l) {
  __builtin_amdgcn_global_load_lds((gbl_u32*)g, (lds_u32*)l, 16, 0, 0);
}

// pair index p (e1<e2): p = 7*e1 - e1*(e1-1)/2 + (e2-e1-1)
__constant__ int cPE1[NPAIR] = {0,0,0,0,0,0,0, 1,1,1,1,1,1, 2,2,2,2,2, 3,3,3,3, 4,4,4, 5,5, 6};
__constant__ int cPE2[NPAIR] = {1,2,3,4,5,6,7, 2,3,4,5,6,7, 3,4,5,6,7, 4,5,6,7, 5,6,7, 6,7, 7};

__global__ void zero_counts(int* counts) {
  if (threadIdx.x < NPAIR) counts[threadIdx.x] = 0;
}

// Gate: tall-skinny GEMM x[16384,2048] @ gw[2048,8] in fp32 (must match
// reference argmax ordering), top-2 with jax tie-break (strict >, lower index
// wins), PAIR-bucket append (unordered {e1,e2}; mean is order-independent),
// fused x -> bf16 conversion.
__global__ __launch_bounds__(256) void gate_topk(
    const float* __restrict__ x, const float* __restrict__ gw,
    const float* __restrict__ gb, unsigned short* __restrict__ xbf,
    int* __restrict__ counts, int* __restrict__ lists) {
  __shared__ float gwT[8 * 2048];  // 64 KB, [e][d]
  const int t = threadIdx.x;
  const float4* gw4 = (const float4*)gw;
#pragma unroll
  for (int j = 0; j < 16; ++j) {
    const int i4 = j * 256 + t;          // float4 index into gw [d][e]
    const float4 v = gw4[i4];
    const int d = i4 >> 1;
    const int eh = (i4 & 1) * 4;
    gwT[(eh + 0) * 2048 + d] = v.x;
    gwT[(eh + 1) * 2048 + d] = v.y;
    gwT[(eh + 2) * 2048 + d] = v.z;
    gwT[(eh + 3) * 2048 + d] = v.w;
  }
  __syncthreads();

  const int wave = t >> 6;
  const int lane = t & 63;
  for (int p = 0; p < 4; ++p) {
    const int tok0 = blockIdx.x * 32 + wave * 8 + p * 2;
    const float* xr0 = x + (size_t)tok0 * DIM;
    unsigned short* xb0 = xbf + (size_t)tok0 * DIM;
    float a0[8] = {0.f, 0.f, 0.f, 0.f, 0.f, 0.f, 0.f, 0.f};
    float a1[8] = {0.f, 0.f, 0.f, 0.f, 0.f, 0.f, 0.f, 0.f};
#pragma unroll
    for (int it = 0; it < 8; ++it) {
      const int d0 = it * 256 + lane * 4;
      const float4 x0 = *(const float4*)(xr0 + d0);
      const float4 x1 = *(const float4*)(xr0 + DIM + d0);
      ushort4 p0, p1;
      p0.x = f2bf(x0.x); p0.y = f2bf(x0.y); p0.z = f2bf(x0.z); p0.w = f2bf(x0.w);
      p1.x = f2bf(x1.x); p1.y = f2bf(x1.y); p1.z = f2bf(x1.z); p1.w = f2bf(x1.w);
      *(ushort4*)(xb0 + d0) = p0;
      *(ushort4*)(xb0 + DIM + d0) = p1;
#pragma unroll
      for (int e = 0; e < 8; ++e) {
        const float4 g = *(const float4*)(&gwT[e * 2048 + d0]);
        a0[e] += x0.x * g.x + x0.y * g.y + x0.z * g.z + x0.w * g.w;
        a1[e] += x1.x * g.x + x1.y * g.y + x1.z * g.z + x1.w * g.w;
      }
    }
#pragma unroll
    for (int e = 0; e < 8; ++e) {
#pragma unroll
      for (int off = 32; off > 0; off >>= 1) {
        a0[e] += __shfl_xor(a0[e], off);
        a1[e] += __shfl_xor(a1[e], off);
      }
    }
    // After butterfly every lane holds the full sums: lane 0 finalizes tok0,
    // lane 1 finalizes tok0+1 (independent atomics).
    if (lane < 2) {
      const float* aa = (lane == 0) ? a0 : a1;
      const int tok = tok0 + lane;
      float bv = -3.4e38f, sv = -3.4e38f;
      int bi = 0, si = 0;
#pragma unroll
      for (int ee = 0; ee < 8; ++ee) {
        const float v = aa[ee] + gb[ee];
        if (v > bv) { sv = bv; si = bi; bv = v; bi = ee; }
        else if (v > sv) { sv = v; si = ee; }
      }
      const int e1 = (bi < si) ? bi : si;
      const int e2 = (bi < si) ? si : bi;
      const int pi = 7 * e1 - (e1 * (e1 - 1)) / 2 + (e2 - e1 - 1);
      const int pos = atomicAdd(&counts[pi], 1);
      lists[(size_t)pi * NS_TOK + pos] = tok;
    }
  }
}

// expert_w [e][d][o] fp32 -> wT [e][o][d] bf16 via 64x64 LDS tile.
__global__ __launch_bounds__(256) void wconv(const float* __restrict__ w,
                                             unsigned short* __restrict__ wt) {
  __shared__ unsigned short s[64 * 66];  // pitch 66 -> phase-2 reads conflict-light
  const int e = blockIdx.z;
  const int d0 = blockIdx.y * 64;
  const int o0 = blockIdx.x * 64;
  const int t = threadIdx.x;
  const float* wp = w + (size_t)e * DIM * OUTD + (size_t)d0 * OUTD + o0;
#pragma unroll
  for (int p = 0; p < 4; ++p) {
    const int lin = p * 1024 + t * 4;
    const int dl = lin >> 6;
    const int ol = lin & 63;
    const float4 v = *(const float4*)(wp + (size_t)dl * OUTD + ol);
    uint32_t* sp = (uint32_t*)&s[dl * 66 + ol];
    sp[0] = (uint32_t)f2bf(v.x) | ((uint32_t)f2bf(v.y) << 16);
    sp[1] = (uint32_t)f2bf(v.z) | ((uint32_t)f2bf(v.w) << 16);
  }
  __syncthreads();
  unsigned short* wtp = wt + (size_t)e * OUTD * DIM + (size_t)o0 * DIM + d0;
#pragma unroll
  for (int p = 0; p < 2; ++p) {
    const int idx8 = p * 256 + t;
    const int ol2 = idx8 >> 3;
    const int dl2 = (idx8 & 7) * 8;
    ushort4 a, b;
    a.x = s[(dl2 + 0) * 66 + ol2]; a.y = s[(dl2 + 1) * 66 + ol2];
    a.z = s[(dl2 + 2) * 66 + ol2]; a.w = s[(dl2 + 3) * 66 + ol2];
    b.x = s[(dl2 + 4) * 66 + ol2]; b.y = s[(dl2 + 5) * 66 + ol2];
    b.z = s[(dl2 + 6) * 66 + ol2]; b.w = s[(dl2 + 7) * 66 + ol2];
    ushort4* op = (ushort4*)(wtp + (size_t)ol2 * DIM + dl2);
    op[0] = a; op[1] = b;
  }
}

// Fused pair GEMM: 128 tokens x 128 cols x BOTH experts of the pair.
// BK=64, mfma 16x16x32 bf16, 4 waves 2x2. A-tile staged ONCE feeds 2x MFMA.
// XOR-granule swizzle on the global-fetch side (global_load_lds dest is
// base+lane*16) so fragment ds_read_b128 are conflict-free.
// Epilogue writes 0.5*(relu1+relu2) once: kills SET1's 268 MB out RMW.
__global__ __launch_bounds__(256, 2) void moe_gemm_pair(
    const unsigned short* __restrict__ xbf, const unsigned short* __restrict__ wt,
    const float* __restrict__ eb, const int* __restrict__ counts,
    const int* __restrict__ lists, float* __restrict__ out) {
  const int p = blockIdx.z;
  const int cnt = counts[p];
  const int r0 = blockIdx.y * 128;
  if (r0 >= cnt) return;
  const int e1 = cPE1[p];
  const int e2 = cPE2[p];

  __shared__ unsigned short sA[128 * 64];
  __shared__ unsigned short sB1[128 * 64];
  __shared__ unsigned short sB2[128 * 64];
  __shared__ int s_tok[128];

  const int tid = threadIdx.x;
  const int lane = tid & 63;
  const int w = tid >> 6;

  const int* lp = lists + (size_t)p * NS_TOK + r0;
  if (tid < 128) s_tok[tid] = (r0 + tid < cnt) ? lp[tid] : lp[0];
  __syncthreads();

  // Per-thread staging pointers: 4 rounds x 256 threads x 16B = 16KB tile.
  const unsigned short* agp[4];
  const unsigned short* b1gp[4];
  const size_t eoff = (size_t)(e2 - e1) * OUTD * DIM;  // uniform: B2 = B1 + eoff
  const int gsub = tid & 7;
#pragma unroll
  for (int rd = 0; rd < 4; ++rd) {
    const int row = rd * 32 + (tid >> 3);       // 0..127 within tile
    const int gp = gsub ^ (row & 7);            // swizzled 16B granule
    agp[rd] = xbf + (size_t)s_tok[row] * DIM + gp * 8;
    const int ncol = blockIdx.x * 128 + row;
    b1gp[rd] = wt + (size_t)e1 * OUTD * DIM + (size_t)ncol * DIM + gp * 8;
  }

  const int wrow = (w & 1) * 64;
  const int wcol = (w >> 1) * 64;
  const int kq = lane >> 4;
  const int l7 = lane & 7;
  const int ko[2] = {(kq ^ l7) * 16, ((4 + kq) ^ l7) * 16};
  int arow[4], brow[4];
#pragma unroll
  for (int i = 0; i < 4; ++i) {
    arow[i] = (wrow + i * 16 + (lane & 15)) * 128;
    brow[i] = (wcol + i * 16 + (lane & 15)) * 128;
  }

  f32x4 acc1[4][4] = {};
  f32x4 acc2[4][4] = {};
  char* sAc = (char*)sA;
  char* sB1c = (char*)sB1;
  char* sB2c = (char*)sB2;

  for (int kt = 0; kt < DIM / 64; ++kt) {
#pragma unroll
    for (int rd = 0; rd < 4; ++rd) {
      gld_lds16(agp[rd], sAc + (rd * 256 + w * 64) * 16);
      gld_lds16(b1gp[rd], sB1c + (rd * 256 + w * 64) * 16);
      gld_lds16(b1gp[rd] + eoff, sB2c + (rd * 256 + w * 64) * 16);
      agp[rd] += 64;  // 64 bf16 = 128B per K-tile
      b1gp[rd] += 64;
    }
    __syncthreads();  // vmcnt(0) drain: staging visible
#pragma unroll
    for (int c = 0; c < 2; ++c) {
      short8 av[4], bv[4];
#pragma unroll
      for (int i = 0; i < 4; ++i) av[i] = *(const short8*)(sAc + arow[i] + ko[c]);
#pragma unroll
      for (int i = 0; i < 4; ++i) bv[i] = *(const short8*)(sB1c + brow[i] + ko[c]);
      __builtin_amdgcn_s_setprio(1);
#pragma unroll
      for (int mi = 0; mi < 4; ++mi)
#pragma unroll
        for (int ni = 0; ni < 4; ++ni)
          acc1[mi][ni] = __builtin_amdgcn_mfma_f32_16x16x32_bf16(
              av[mi], bv[ni], acc1[mi][ni], 0, 0, 0);
      __builtin_amdgcn_s_setprio(0);
#pragma unroll
      for (int i = 0; i < 4; ++i) bv[i] = *(const short8*)(sB2c + brow[i] + ko[c]);
      __builtin_amdgcn_s_setprio(1);
#pragma unroll
      for (int mi = 0; mi < 4; ++mi)
#pragma unroll
        for (int ni = 0; ni < 4; ++ni)
          acc2[mi][ni] = __builtin_amdgcn_mfma_f32_16x16x32_bf16(
              av[mi], bv[ni], acc2[mi][ni], 0, 0, 0);
      __builtin_amdgcn_s_setprio(0);
    }
    __syncthreads();  // all reads done before next overwrite
  }

  // Epilogue. C layout: col = lane&15, row = (lane>>4)*4 + reg (m89-verified).
  const int colb = blockIdx.x * 128 + wcol + (lane & 15);
  float bia1[4], bia2[4];
#pragma unroll
  for (int ni = 0; ni < 4; ++ni) {
    bia1[ni] = eb[e1 * OUTD + colb + ni * 16];
    bia2[ni] = eb[e2 * OUTD + colb + ni * 16];
  }
#pragma unroll
  for (int mi = 0; mi < 4; ++mi) {
#pragma unroll
    for (int r = 0; r < 4; ++r) {
      const int rl = wrow + mi * 16 + (lane >> 4) * 4 + r;
      if (r0 + rl < cnt) {
        float* orow = out + (size_t)s_tok[rl] * OUTD;
#pragma unroll
        for (int ni = 0; ni < 4; ++ni) {
          const float v1 = fmaxf(acc1[mi][ni][r] + bia1[ni], 0.0f);
          const float v2 = fmaxf(acc2[mi][ni][r] + bia2[ni], 0.0f);
          orow[colb + ni * 16] = 0.5f * (v1 + v2);
        }
      }
    }
  }
}

extern "C" void kernel_launch(void* const* d_in, const int* in_sizes, int n_in,
                              void* d_out, int out_size, void* d_ws, size_t ws_size,
                              hipStream_t stream) {
  const float* x  = (const float*)d_in[0];
  const float* gw = (const float*)d_in[1];
  const float* gb = (const float*)d_in[2];
  const float* ew = (const float*)d_in[3];
  const float* eb = (const float*)d_in[4];
  float* out = (float*)d_out;

  char* ws = (char*)d_ws;
  // ws layout: x_bf16 64MB | wT_bf16 64MB | counts 256B | pair-lists 1.75MB
  unsigned short* xbf = (unsigned short*)(ws);
  unsigned short* wt  = (unsigned short*)(ws + 67108864);
  int* counts         = (int*)(ws + 134217728);
  int* lists          = (int*)(ws + 134217984);

  zero_counts<<<1, 64, 0, stream>>>(counts);
  gate_topk<<<NS_TOK / 32, 256, 0, stream>>>(x, gw, gb, xbf, counts, lists);
  wconv<<<dim3(OUTD / 64, DIM / 64, NEXP), 256, 0, stream>>>(ew, wt);
  moe_gemm_pair<<<dim3(OUTD / 128, NS_TOK / 128, NPAIR), 256, 0, stream>>>(
      xbf, wt, eb, counts, lists, out);
}